// Round 11
// baseline (515.406 us; speedup 1.0000x reference)
//
#include <hip/hip_runtime.h>

#define NY 512
#define NX 512
#define NSHOT 4
#define NSRC 2
#define NREC 64
#define NT 32
#define DTF 0.0005f
#define PML_W 20
#define C1F 1.125f
#define C2F (-1.0f/24.0f)
#define INV_DX 0.2f

// pad-4 field layout: [520][520] per shot, interior at (4,4). Ring cells
// (width 4) stay zero forever -> staging reads up to +-4 are unconditional.
#define PS 520
#define PFS (PS*PS)
#define TILE 32

// Compact PML m-field storage: each m-field is nonzero only in its 40-wide
// strip. y-type: [shot][40][512] (rows 0..19 and 492..511 -> yy = y or y-472).
// x-type: [shot][512][40] (cols -> xx = x or x-472).
#define MSTRIP (40*512)
#define MTOT (8*NSHOT*MSTRIP)
#define MF_SYYY (0*NSHOT*MSTRIP)
#define MF_SXYY (1*NSHOT*MSTRIP)
#define MF_SXYX (2*NSHOT*MSTRIP)
#define MF_SXXX (3*NSHOT*MSTRIP)
#define MF_VYY  (4*NSHOT*MSTRIP)
#define MF_VXY  (5*NSHOT*MSTRIP)
#define MF_VXX  (6*NSHOT*MSTRIP)
#define MF_VYX  (7*NSHOT*MSTRIP)

__device__ __forceinline__ bool in_pml(int i) {
    return (i < PML_W) | (i >= NY - PML_W);
}

__global__ void init_profiles(float* __restrict__ pa, float* __restrict__ pb) {
    int i = blockIdx.x * blockDim.x + threadIdx.x;
    if (i >= NY) return;
    float w = (float)PML_W;
    float x = (float)i;
    float frac = fmaxf((w - x) / w, (x - (float)(NY - 1 - PML_W)) / w);
    frac = fminf(fmaxf(frac, 0.0f), 1.0f);
    float sigma = 3.0f * 3500.0f * 6.9077553f / (2.0f * w * 5.0f) * frac * frac;
    float alpha = 78.539816f; // pi * 25
    float b = __expf(-(sigma + alpha) * DTF);
    pb[i] = b;
    pa[i] = sigma / (sigma + alpha) * (b - 1.0f);
}

// Light-cone gate for a 32x32 tile. Fields start exactly 0 and stay exactly
// +0.0 outside the cone (IEEE 0-propagation), identical to the reference's
// zeros. Support radii (L-inf): vel(t)=4t, stress(t)=4t+2; gate with
// R=4t+8 (slack 6). Skipped tiles' W-buffers remain memset-zero = the exact
// value they would compute (cones grow monotonically, so both ping-pong
// buffers are zero outside the cone); receivers in skipped tiles keep the
// harness's out-memset 0 = the reference's exact 0.
__device__ __forceinline__ bool cone_active(const int* __restrict__ srcloc,
                                            int s, int gy0, int gx0, int R) {
    bool act = false;
#pragma unroll
    for (int i = 0; i < NSRC; ++i) {
        int sy = srcloc[(s * NSRC + i) * 2 + 0];
        int sx = srcloc[(s * NSRC + i) * 2 + 1];
        act |= (sy >= gy0 - R) & (sy <= gy0 + 31 + R) &
               (sx >= gx0 - R) & (sx <= gx0 + 31 + R);
    }
    return act;
}

// Fused vel+stress, one timestep per launch (round-7 verified bit-exact),
// with light-cone tile gating. 1024 blocks = 4 shots x 16x16 tiles of 32x32;
// c = (b&7)*128 + (b>>3) gives XCD k a contiguous half-shot band.
// Phase 1: stage old stress [40][40] -> LDS; compute NEW vel on the
// extended 36x36 region into LDS (ring cells recomputed redundantly by
// neighbors from identical inputs -> identical bits). Phase 2: compute
// stress on the 32x32 core from LDS vel. All global reads hit the R
// (t-1) buffers, all writes the W (t) buffers -> race-free multi-launch.
template<bool FIRST>
__global__ __launch_bounds__(256, 4) void fused_kernel(
    const float* __restrict__ Rvy, const float* __restrict__ Rvx,
    const float* __restrict__ Rsyy, const float* __restrict__ Rsxy,
    const float* __restrict__ Rsxx,
    float* __restrict__ Wvy, float* __restrict__ Wvx,
    float* __restrict__ Wsyy, float* __restrict__ Wsxy,
    float* __restrict__ Wsxx,
    const float* __restrict__ RM, float* __restrict__ WM,
    const float* __restrict__ buoy, const float* __restrict__ lamb,
    const float* __restrict__ mu,
    const float* __restrict__ pa, const float* __restrict__ pb,
    const float* __restrict__ amps, const int* __restrict__ srcloc,
    const int* __restrict__ recloc, float* __restrict__ out, int t)
{
    __shared__ float sS[3][40 * 40];   // staged old syy, sxy, sxx
    __shared__ float sV[2][36 * 36];   // new vy, vx (extended region)

    const int b   = (int)blockIdx.x;
    const int c   = (b & 7) * 128 + (b >> 3);
    const int s   = c >> 8;
    const int tr  = (c >> 4) & 15;
    const int tc  = c & 15;
    const int tid = (int)threadIdx.x;
    const int gy0 = tr * TILE, gx0 = tc * TILE;
    const size_t sb0 = (size_t)s * PFS;

    // light-cone gate (before any write)
    if (!cone_active(srcloc, s, gy0, gx0, 4 * t + 8)) return;

    // ---- stage old stress on [gy0-4, gy0+36) x [gx0-4, gx0+36) ----
    if (!FIRST) {
        for (int i = tid; i < 1600; i += 256) {
            int row = i / 40, col = i - row * 40;
            size_t g = sb0 + (size_t)(gy0 + row) * PS + (gx0 + col); // (gy0-4+row)+4
            sS[0][i] = Rsyy[g];
            sS[1][i] = Rsxy[g];
            sS[2][i] = Rsxx[g];
        }
        __syncthreads();
    }

    const int sy0 = srcloc[(s * NSRC + 0) * 2 + 0];
    const int sx0 = srcloc[(s * NSRC + 0) * 2 + 1];
    const int sy1 = srcloc[(s * NSRC + 1) * 2 + 0];
    const int sx1 = srcloc[(s * NSRC + 1) * 2 + 1];

    // ---- phase 1: velocity on extended 36x36 ----
    for (int i = tid; i < 1296; i += 256) {
        int ey = i / 36, ex = i - ey * 36;
        int gy = gy0 - 2 + ey, gx = gx0 - 2 + ex;
        float vy_new = 0.0f, vx_new = 0.0f;
        if (((unsigned)gy < (unsigned)NY) && ((unsigned)gx < (unsigned)NX)) {
            const int sb = (ey + 2) * 40 + (ex + 2);
            const bool core = (ey >= 2) & (ey < 34) & (ex >= 2) & (ex < 34);

            float syy_0  = FIRST ? 0.0f : sS[0][sb];
            float syy_m1 = FIRST ? 0.0f : sS[0][sb - 40];
            float syy_m2 = FIRST ? 0.0f : sS[0][sb - 80];
            float syy_p1 = FIRST ? 0.0f : sS[0][sb + 40];
            float dsyy = (C1F * (syy_0 - syy_m1) + C2F * (syy_p1 - syy_m2)) * INV_DX;

            float sxy_0   = FIRST ? 0.0f : sS[1][sb];
            float sxy_xm1 = FIRST ? 0.0f : sS[1][sb - 1];
            float sxy_xp1 = FIRST ? 0.0f : sS[1][sb + 1];
            float sxy_xp2 = FIRST ? 0.0f : sS[1][sb + 2];
            float dsxy_x = (C1F * (sxy_xp1 - sxy_0) + C2F * (sxy_xp2 - sxy_xm1)) * INV_DX;

            float sxy_ym1 = FIRST ? 0.0f : sS[1][sb - 40];
            float sxy_yp1 = FIRST ? 0.0f : sS[1][sb + 40];
            float sxy_yp2 = FIRST ? 0.0f : sS[1][sb + 80];
            float dsxy_y = (C1F * (sxy_yp1 - sxy_0) + C2F * (sxy_yp2 - sxy_ym1)) * INV_DX;

            float sxx_0   = FIRST ? 0.0f : sS[2][sb];
            float sxx_xm1 = FIRST ? 0.0f : sS[2][sb - 1];
            float sxx_xm2 = FIRST ? 0.0f : sS[2][sb - 2];
            float sxx_xp1 = FIRST ? 0.0f : sS[2][sb + 1];
            float dsxx = (C1F * (sxx_0 - sxx_xm1) + C2F * (sxx_xp1 - sxx_xm2)) * INV_DX;

            float msyyy = 0.0f, msxyy = 0.0f;
            if (in_pml(gy)) {
                float ay = pa[gy], by = pb[gy];
                int yy = (gy < PML_W) ? gy : gy - 472;
                int mo = (s * 40 + yy) * 512 + gx;
                float mo1 = FIRST ? 0.0f : RM[MF_SYYY + mo];
                float mo2 = FIRST ? 0.0f : RM[MF_SXYY + mo];
                msyyy = by * mo1 + ay * dsyy;
                msxyy = by * mo2 + ay * dsxy_y;
                if (core) { WM[MF_SYYY + mo] = msyyy; WM[MF_SXYY + mo] = msxyy; }
            }
            float msxyx = 0.0f, msxxx = 0.0f;
            if (in_pml(gx)) {
                float ax = pa[gx], bx = pb[gx];
                int xx = (gx < PML_W) ? gx : gx - 472;
                int mo = (s * 512 + gy) * 40 + xx;
                float mo1 = FIRST ? 0.0f : RM[MF_SXYX + mo];
                float mo2 = FIRST ? 0.0f : RM[MF_SXXX + mo];
                msxyx = bx * mo1 + ax * dsxy_x;
                msxxx = bx * mo2 + ax * dsxx;
                if (core) { WM[MF_SXYX + mo] = msxyx; WM[MF_SXXX + mo] = msxxx; }
            }

            size_t g = sb0 + (size_t)(gy + 4) * PS + (gx + 4);
            float bb  = buoy[gy * NX + gx];
            float vyo = FIRST ? 0.0f : Rvy[g];
            float vxo = FIRST ? 0.0f : Rvx[g];
            vy_new = vyo + DTF * bb * ((dsyy + msyyy) + (dsxy_x + msxyx));
            vx_new = vxo + DTF * bb * ((dsxy_y + msxyy) + (dsxx + msxxx));

            if (gy == sy0 && gx == sx0)
                vy_new += amps[(s * NSRC + 0) * NT + t] * DTF * bb;
            if (gy == sy1 && gx == sx1)
                vy_new += amps[(s * NSRC + 1) * NT + t] * DTF * bb;
        }
        sV[0][i] = vy_new;
        sV[1][i] = vx_new;
    }
    __syncthreads();

    // receivers: vy(t) of this tile, from LDS (exactly one owning block;
    // receivers in gated-off tiles keep the harness's 0 = exact reference 0)
    if (tid < NREC) {
        int ry = recloc[(s * NREC + tid) * 2 + 0];
        int rx = recloc[(s * NREC + tid) * 2 + 1];
        if (((ry >> 5) == tr) && ((rx >> 5) == tc))
            out[(s * NREC + tid) * NT + t] =
                sV[0][((ry & 31) + 2) * 36 + ((rx & 31) + 2)];
    }

    // ---- phase 2: stress on 32x32 core ----
    for (int i = tid; i < 1024; i += 256) {
        int cy = i >> 5, cx = i & 31;
        int gy = gy0 + cy, gx = gx0 + cx;
        const int vb = (cy + 2) * 36 + (cx + 2);

        float vy_0   = sV[0][vb];
        float vy_ym1 = sV[0][vb - 36];
        float vy_yp1 = sV[0][vb + 36];
        float vy_yp2 = sV[0][vb + 72];
        float dvyy = (C1F * (vy_yp1 - vy_0) + C2F * (vy_yp2 - vy_ym1)) * INV_DX;

        float vx_0   = sV[1][vb];
        float vx_xm1 = sV[1][vb - 1];
        float vx_xp1 = sV[1][vb + 1];
        float vx_xp2 = sV[1][vb + 2];
        float dvxx = (C1F * (vx_xp1 - vx_0) + C2F * (vx_xp2 - vx_xm1)) * INV_DX;

        float vy_xm1 = sV[0][vb - 1];
        float vy_xm2 = sV[0][vb - 2];
        float vy_xp1 = sV[0][vb + 1];
        float dvyx = (C1F * (vy_0 - vy_xm1) + C2F * (vy_xp1 - vy_xm2)) * INV_DX;

        float vx_ym1 = sV[1][vb - 36];
        float vx_ym2 = sV[1][vb - 72];
        float vx_yp1 = sV[1][vb + 36];
        float dvxy = (C1F * (vx_0 - vx_ym1) + C2F * (vx_yp1 - vx_ym2)) * INV_DX;

        float mvyy = 0.0f, mvxy = 0.0f;
        if (in_pml(gy)) {
            float ay = pa[gy], by = pb[gy];
            int yy = (gy < PML_W) ? gy : gy - 472;
            int mo = (s * 40 + yy) * 512 + gx;
            float mo1 = FIRST ? 0.0f : RM[MF_VYY + mo];
            float mo2 = FIRST ? 0.0f : RM[MF_VXY + mo];
            mvyy = by * mo1 + ay * dvyy;
            mvxy = by * mo2 + ay * dvxy;
            WM[MF_VYY + mo] = mvyy; WM[MF_VXY + mo] = mvxy;
        }
        float mvxx = 0.0f, mvyx = 0.0f;
        if (in_pml(gx)) {
            float ax = pa[gx], bx = pb[gx];
            int xx = (gx < PML_W) ? gx : gx - 472;
            int mo = (s * 512 + gy) * 40 + xx;
            float mo1 = FIRST ? 0.0f : RM[MF_VXX + mo];
            float mo2 = FIRST ? 0.0f : RM[MF_VYX + mo];
            mvxx = bx * mo1 + ax * dvxx;
            mvyx = bx * mo2 + ax * dvyx;
            WM[MF_VXX + mo] = mvxx; WM[MF_VYX + mo] = mvyx;
        }

        float tvyy = dvyy + mvyy;
        float tvxx = dvxx + mvxx;
        float la = lamb[gy * NX + gx];
        float mm = mu[gy * NX + gx];
        float l2m = la + 2.0f * mm;

        const int stb = (cy + 4) * 40 + (cx + 4);     // staged old stress @ core
        float syyo = FIRST ? 0.0f : sS[0][stb];
        float sxyo = FIRST ? 0.0f : sS[1][stb];
        float sxxo = FIRST ? 0.0f : sS[2][stb];

        size_t g = sb0 + (size_t)(gy + 4) * PS + (gx + 4);
        Wsyy[g] = syyo + DTF * (l2m * tvyy + la * tvxx);
        Wsxx[g] = sxxo + DTF * (l2m * tvxx + la * tvyy);
        Wsxy[g] = sxyo + DTF * mm * ((dvyx + mvyx) + (dvxy + mvxy));
        Wvy[g]  = vy_0;
        Wvx[g]  = vx_0;
    }
}

extern "C" void kernel_launch(void* const* d_in, const int* in_sizes, int n_in,
                              void* d_out, int out_size, void* d_ws, size_t ws_size,
                              hipStream_t stream) {
    const float* lamb   = (const float*)d_in[0];
    const float* mu     = (const float*)d_in[1];
    const float* buoy   = (const float*)d_in[2];
    const float* amps   = (const float*)d_in[3];
    const int*   srcloc = (const int*)d_in[4];
    const int*   recloc = (const int*)d_in[5];
    float* out = (float*)d_out;

    float* ws = (float*)d_ws;
    float* pa = ws;
    float* pb = ws + 512;
    const size_t F = (size_t)NSHOT * PFS;       // one padded field (one buffer)
    float* fields = ws + 1024;                  // 10 arrays: [field(5)][buf(2)]
    float* fld[5][2];
    for (int f = 0; f < 5; ++f)
        for (int bu = 0; bu < 2; ++bu)
            fld[f][bu] = fields + ((size_t)f * 2 + bu) * F;
    float* mpool = fields + 10 * F;             // [buf(2)][MTOT]
    float* M[2] = { mpool, mpool + MTOT };

    // Full zero of fields (both buffers) + m-strips: gated-off tiles' W
    // buffers must be exact 0 (= the value they would compute). ~48 MB.
    (void)hipMemsetAsync(fields, 0, (10 * F + 2 * (size_t)MTOT) * sizeof(float), stream);
    init_profiles<<<2, 256, 0, stream>>>(pa, pb);

    dim3 grid(1024), block(256);
    for (int t = 0; t < NT; ++t) {
        int w = t & 1, r = w ^ 1;
        if (t == 0) {
            fused_kernel<true><<<grid, block, 0, stream>>>(
                fld[0][r], fld[1][r], fld[2][r], fld[3][r], fld[4][r],
                fld[0][w], fld[1][w], fld[2][w], fld[3][w], fld[4][w],
                M[r], M[w], buoy, lamb, mu, pa, pb,
                amps, srcloc, recloc, out, t);
        } else {
            fused_kernel<false><<<grid, block, 0, stream>>>(
                fld[0][r], fld[1][r], fld[2][r], fld[3][r], fld[4][r],
                fld[0][w], fld[1][w], fld[2][w], fld[3][w], fld[4][w],
                M[r], M[w], buoy, lamb, mu, pa, pb,
                amps, srcloc, recloc, out, t);
        }
    }
}

// Round 12
// 398.608 us; speedup vs baseline: 1.2930x; 1.2930x over previous
//
#include <hip/hip_runtime.h>

#define NY 512
#define NX 512
#define NSHOT 4
#define NSRC 2
#define NREC 64
#define NT 32
#define DTF 0.0005f
#define PML_W 20
#define C1F 1.125f
#define C2F (-1.0f/24.0f)
#define INV_DX 0.2f

// x-padded layout: row stride 516, interior at x+2 (round-3 verified).
#define NXS 516
#define FSH (NY*NXS)

__device__ __forceinline__ bool in_pml(int i) {
    return (i < PML_W) | (i >= NY - PML_W);
}

__global__ void init_profiles(float* __restrict__ pa, float* __restrict__ pb) {
    int i = blockIdx.x * blockDim.x + threadIdx.x;
    if (i >= NY) return;
    float w = (float)PML_W;
    float x = (float)i;
    float frac = fmaxf((w - x) / w, (x - (float)(NY - 1 - PML_W)) / w);
    frac = fminf(fmaxf(frac, 0.0f), 1.0f);
    float sigma = 3.0f * 3500.0f * 6.9077553f / (2.0f * w * 5.0f) * frac * frac;
    float alpha = 78.539816f; // pi * 25
    float b = __expf(-(sigma + alpha) * DTF);
    pb[i] = b;
    pa[i] = sigma / (sigma + alpha) * (b - 1.0f);
}

// Zero only the PML strips of the 8 m-fields (~3 MB instead of 34 MB):
// m-fields are read/written exclusively under in_pml guards.
// y-type (m_syyy,m_sxyy,m_vyy,m_vxy — layout slots 9,10,5,7): rows
// [0,20)+[492,512), all 516 cols. x-type (m_sxyx,m_sxxx,m_vxx,m_vyx —
// slots 11,12,8,6): padded cols [0,24)+[492,516), all rows.
__global__ void mstrip_zero(float* __restrict__ fields) {
    const size_t F = (size_t)NSHOT * FSH;
    int i = blockIdx.x * blockDim.x + threadIdx.x;
    const int ycnt = NSHOT * 40 * NXS;     // per y-type field
    const int xcnt = NSHOT * NY * 48;      // per x-type field
    if (i < 4 * ycnt) {
        int f = i / ycnt, r = i % ycnt;
        static const int yslot[4] = {9, 10, 5, 7};
        int sh = r / (40 * NXS), rr = r % (40 * NXS);
        int row = rr / NXS, col = rr % NXS;
        row = (row < 20) ? row : 472 + row;                // 20..39 -> 492..511
        fields[yslot[f] * F + (size_t)sh * FSH + row * NXS + col] = 0.0f;
    } else {
        i -= 4 * ycnt;
        if (i >= 4 * xcnt) return;
        int f = i / xcnt, r = i % xcnt;
        static const int xslot[4] = {11, 12, 8, 6};
        int sh = r / (NY * 48), rr = r % (NY * 48);
        int row = rr / 48, c = rr % 48;
        int col = (c < 24) ? c : 468 + c;                  // 24..47 -> 492..515
        fields[xslot[f] * F + (size_t)sh * FSH + row * NXS + col] = 0.0f;
    }
}

// Tile decomposition: 2048 blocks of 512 threads = 64 cols x 8 rows each.
// c = (b&7)*256 + (b>>3) is bijective on [0,2048); XCD k owns c in
// [256k, 256k+256) -> shot k/2, a contiguous 256-row band (verified
// half-shot L2 banding). Within a shot: yg = (c>>3)&63 (8-row group),
// xt = c&7 (64-col tile).
__device__ __forceinline__ void tile_decode(int& s, int& y0, int& x0) {
    int b = (int)blockIdx.x;
    int c = (b & 7) * 256 + (b >> 3);
    s  = c >> 9;
    y0 = ((c >> 3) & 63) * 8;
    x0 = (c & 7) * 64;
}

// Light-cone activity test on a 64x8 tile (round-10 verified semantics).
// Fields start exactly 0 and stay exactly +0.0 outside the cone (IEEE
// 0-propagation), identical to the reference's zeros. Support radii
// (L-inf): vel(t)=4t, stress(t)=4t+2; gate with slack R_vel=4t+6,
// R_stress=4t+8. Inactive tiles return without touching memory.
__device__ __forceinline__ bool cone_active(const int* __restrict__ srcloc,
                                            int s, int y0, int x0, int R) {
    bool act = false;
#pragma unroll
    for (int i = 0; i < NSRC; ++i) {
        int sy = srcloc[(s * NSRC + i) * 2 + 0];
        int sx = srcloc[(s * NSRC + i) * 2 + 1];
        act |= (sy >= y0 - R) & (sy <= y0 + 7 + R) &
               (sx >= x0 - R) & (sx <= x0 + 63 + R);
    }
    return act;
}

__global__ __launch_bounds__(512) void vel_kernel(
    const float* __restrict__ syy, const float* __restrict__ sxy, const float* __restrict__ sxx,
    float* __restrict__ vy, float* __restrict__ vx,
    float* __restrict__ m_syyy, float* __restrict__ m_sxyy,
    float* __restrict__ m_sxyx, float* __restrict__ m_sxxx,
    const float* __restrict__ buoy,
    const float* __restrict__ pa, const float* __restrict__ pb,
    const float* __restrict__ amps, const int* __restrict__ srcloc, int t)
{
    int s, y0, x0;
    tile_decode(s, y0, x0);
    if (!cone_active(srcloc, s, y0, x0, 4 * t + 6)) return;

    int x = x0 + ((int)threadIdx.x & 63);
    int y = y0 + ((int)threadIdx.x >> 6);       // wave-uniform (wave = one row)
    int idx = s * FSH + y * NXS + x + 2;

    // wave-uniform y-guards
    const bool gm2 = (y >= 2);
    const bool gm1 = (y >= 1);
    const bool gp1 = (y <= NY - 2);
    const bool gp2 = (y <= NY - 3);

    // dsyy = diff_minus(syy, y)
    float syy_0  = syy[idx];
    float syy_m1 = gm1 ? syy[idx - NXS] : 0.0f;
    float syy_m2 = gm2 ? syy[idx - 2 * NXS] : 0.0f;
    float syy_p1 = gp1 ? syy[idx + NXS] : 0.0f;
    float dsyy = (C1F * (syy_0 - syy_m1) + C2F * (syy_p1 - syy_m2)) * INV_DX;

    // dsxy_x = diff_plus(sxy, x)
    float sxy_0   = sxy[idx];
    float sxy_xm1 = sxy[idx - 1];
    float sxy_xp1 = sxy[idx + 1];
    float sxy_xp2 = sxy[idx + 2];
    float dsxy_x = (C1F * (sxy_xp1 - sxy_0) + C2F * (sxy_xp2 - sxy_xm1)) * INV_DX;

    // dsxy_y = diff_plus(sxy, y)
    float sxy_ym1 = gm1 ? sxy[idx - NXS] : 0.0f;
    float sxy_yp1 = gp1 ? sxy[idx + NXS] : 0.0f;
    float sxy_yp2 = gp2 ? sxy[idx + 2 * NXS] : 0.0f;
    float dsxy_y = (C1F * (sxy_yp1 - sxy_0) + C2F * (sxy_yp2 - sxy_ym1)) * INV_DX;

    // dsxx = diff_minus(sxx, x)
    float sxx_0   = sxx[idx];
    float sxx_xm1 = sxx[idx - 1];
    float sxx_xm2 = sxx[idx - 2];
    float sxx_xp1 = sxx[idx + 1];
    float dsxx = (C1F * (sxx_0 - sxx_xm1) + C2F * (sxx_xp1 - sxx_xm2)) * INV_DX;

    // y-direction PML memory fields (wave-uniform branch)
    float msyyy = 0.0f, msxyy = 0.0f;
    if (in_pml(y)) {
        float ay = pa[y], by = pb[y];
        msyyy = by * m_syyy[idx] + ay * dsyy;   m_syyy[idx] = msyyy;
        msxyy = by * m_sxyy[idx] + ay * dsxy_y; m_sxyy[idx] = msxyy;
    }
    // x-direction PML memory fields (lane-masked)
    float msxyx = 0.0f, msxxx = 0.0f;
    if (in_pml(x)) {
        float ax = pa[x], bx = pb[x];
        msxyx = bx * m_sxyx[idx] + ax * dsxy_x; m_sxyx[idx] = msxyx;
        msxxx = bx * m_sxxx[idx] + ax * dsxx;   m_sxxx[idx] = msxxx;
    }

    float b = buoy[y * NX + x];
    float vy_new = vy[idx] + DTF * b * ((dsyy + msyyy) + (dsxy_x + msxyx));
    vx[idx] += DTF * b * ((dsxy_y + msxyy) + (dsxx + msxxx));

    // source injection (after velocity update, before stress pass reads vy)
#pragma unroll
    for (int i = 0; i < NSRC; ++i) {
        int sy = srcloc[(s * NSRC + i) * 2 + 0];
        int sx = srcloc[(s * NSRC + i) * 2 + 1];
        if (sy == y && sx == x) {
            vy_new += amps[(s * NSRC + i) * NT + t] * DTF * b;
        }
    }
    vy[idx] = vy_new;
}

__global__ __launch_bounds__(512) void stress_kernel_gated(
    const float* __restrict__ vy, const float* __restrict__ vx,
    float* __restrict__ syy, float* __restrict__ sxy, float* __restrict__ sxx,
    float* __restrict__ m_vyy, float* __restrict__ m_vyx,
    float* __restrict__ m_vxy, float* __restrict__ m_vxx,
    const float* __restrict__ lamb, const float* __restrict__ mu,
    const float* __restrict__ pa, const float* __restrict__ pb,
    const int* __restrict__ recloc, float* __restrict__ out,
    const int* __restrict__ srcloc, int t)
{
    int s, y0, x0;
    tile_decode(s, y0, x0);

    // receiver recording BEFORE the cone gate (vy is exactly 0 outside the
    // cone — matches the reference's zeros). 256 = NSHOT*NREC <= 512.
    if (blockIdx.x == 0) {
        int p = threadIdx.x;
        if (p < NSHOT * NREC) {
            int sh = p / NREC;
            int ry = recloc[p * 2 + 0];
            int rx = recloc[p * 2 + 1];
            out[p * NT + t] = vy[sh * FSH + ry * NXS + rx + 2];
        }
    }
    if (!cone_active(srcloc, s, y0, x0, 4 * t + 8)) return;

    int x = x0 + ((int)threadIdx.x & 63);
    int y = y0 + ((int)threadIdx.x >> 6);       // wave-uniform
    int idx = s * FSH + y * NXS + x + 2;

    const bool gm2 = (y >= 2);
    const bool gm1 = (y >= 1);
    const bool gp1 = (y <= NY - 2);
    const bool gp2 = (y <= NY - 3);

    // dvyy = diff_plus(vy, y)
    float vy_0   = vy[idx];
    float vy_ym1 = gm1 ? vy[idx - NXS] : 0.0f;
    float vy_yp1 = gp1 ? vy[idx + NXS] : 0.0f;
    float vy_yp2 = gp2 ? vy[idx + 2 * NXS] : 0.0f;
    float dvyy = (C1F * (vy_yp1 - vy_0) + C2F * (vy_yp2 - vy_ym1)) * INV_DX;

    // dvxx = diff_plus(vx, x)
    float vx_0   = vx[idx];
    float vx_xm1 = vx[idx - 1];
    float vx_xp1 = vx[idx + 1];
    float vx_xp2 = vx[idx + 2];
    float dvxx = (C1F * (vx_xp1 - vx_0) + C2F * (vx_xp2 - vx_xm1)) * INV_DX;

    // dvyx = diff_minus(vy, x)
    float vy_xm1 = vy[idx - 1];
    float vy_xm2 = vy[idx - 2];
    float vy_xp1 = vy[idx + 1];
    float dvyx = (C1F * (vy_0 - vy_xm1) + C2F * (vy_xp1 - vy_xm2)) * INV_DX;

    // dvxy = diff_minus(vx, y)
    float vx_ym1 = gm1 ? vx[idx - NXS] : 0.0f;
    float vx_ym2 = gm2 ? vx[idx - 2 * NXS] : 0.0f;
    float vx_yp1 = gp1 ? vx[idx + NXS] : 0.0f;
    float dvxy = (C1F * (vx_0 - vx_ym1) + C2F * (vx_yp1 - vx_ym2)) * INV_DX;

    float mvyy = 0.0f, mvxy = 0.0f;
    if (in_pml(y)) {
        float ay = pa[y], by = pb[y];
        mvyy = by * m_vyy[idx] + ay * dvyy; m_vyy[idx] = mvyy;
        mvxy = by * m_vxy[idx] + ay * dvxy; m_vxy[idx] = mvxy;
    }
    float mvxx = 0.0f, mvyx = 0.0f;
    if (in_pml(x)) {
        float ax = pa[x], bx = pb[x];
        mvxx = bx * m_vxx[idx] + ax * dvxx; m_vxx[idx] = mvxx;
        mvyx = bx * m_vyx[idx] + ax * dvyx; m_vyx[idx] = mvyx;
    }

    float tvyy = dvyy + mvyy;
    float tvxx = dvxx + mvxx;

    float la = lamb[y * NX + x];
    float m  = mu[y * NX + x];
    float l2m = la + 2.0f * m;
    syy[idx] += DTF * (l2m * tvyy + la * tvxx);
    sxx[idx] += DTF * (l2m * tvxx + la * tvyy);
    sxy[idx] += DTF * m * ((dvyx + mvyx) + (dvxy + mvxy));
}

extern "C" void kernel_launch(void* const* d_in, const int* in_sizes, int n_in,
                              void* d_out, int out_size, void* d_ws, size_t ws_size,
                              hipStream_t stream) {
    const float* lamb   = (const float*)d_in[0];
    const float* mu     = (const float*)d_in[1];
    const float* buoy   = (const float*)d_in[2];
    const float* amps   = (const float*)d_in[3];
    const int*   srcloc = (const int*)d_in[4];
    const int*   recloc = (const int*)d_in[5];
    float* out = (float*)d_out;

    float* ws = (float*)d_ws;
    float* pa = ws;
    float* pb = ws + 512;
    const size_t F = (size_t)NSHOT * FSH;
    float* fields = ws + 1024;
    float* vy     = fields + 0  * F;
    float* vx     = fields + 1  * F;
    float* syy    = fields + 2  * F;
    float* sxy    = fields + 3  * F;
    float* sxx    = fields + 4  * F;
    float* m_vyy  = fields + 5  * F;
    float* m_vyx  = fields + 6  * F;
    float* m_vxy  = fields + 7  * F;
    float* m_vxx  = fields + 8  * F;
    float* m_syyy = fields + 9  * F;
    float* m_sxyy = fields + 10 * F;
    float* m_sxyx = fields + 11 * F;
    float* m_sxxx = fields + 12 * F;

    // Zero init, reduced: full memset of the 5 stencil fields (~21 MB;
    // the cone gate requires untouched cells to be exact 0), plus the PML
    // strips of the 8 m-fields (~3 MB; m-fields are only accessed under
    // in_pml guards).
    (void)hipMemsetAsync(fields, 0, 5 * F * sizeof(float), stream);
    {
        int total = 4 * NSHOT * 40 * NXS + 4 * NSHOT * NY * 48;
        mstrip_zero<<<(total + 255) / 256, 256, 0, stream>>>(fields);
    }
    init_profiles<<<2, 256, 0, stream>>>(pa, pb);

    dim3 grid(2048);
    dim3 block(512);
    for (int t = 0; t < NT; ++t) {
        vel_kernel<<<grid, block, 0, stream>>>(syy, sxy, sxx, vy, vx,
                                               m_syyy, m_sxyy, m_sxyx, m_sxxx,
                                               buoy, pa, pb, amps, srcloc, t);
        stress_kernel_gated<<<grid, block, 0, stream>>>(vy, vx, syy, sxy, sxx,
                                                        m_vyy, m_vyx, m_vxy, m_vxx,
                                                        lamb, mu, pa, pb, recloc, out,
                                                        srcloc, t);
    }
}